// Round 9
// baseline (659.190 us; speedup 1.0000x reference)
//
#include <hip/hip_runtime.h>
#include <stdint.h>

#define N_NODES 50000
#define N_EDGES 800000
#define IN_F 128
#define HEADS 8
#define HEAD_DIM 16
#define ALPHA 0.2f
#define EPSV 1e-6f

__device__ __forceinline__ float bf2f(unsigned v) {
    return __uint_as_float(v << 16);
}
__device__ __forceinline__ unsigned f2bf(float f) {
    unsigned u = __float_as_uint(f);
    return (u + 0x7fffu + ((u >> 16) & 1u)) >> 16;
}

// ---------------- init: zero deg
__global__ __launch_bounds__(256) void k_init(int* __restrict__ deg) {
    int i = blockIdx.x * 256 + threadIdx.x;
    if (i < N_NODES) deg[i] = 0;
}

// ---------------- wt: transpose W[h][f][d] -> WT[c][f]  (c = h*16+d)
__global__ __launch_bounds__(256) void k_wt(const float* __restrict__ W,
                                            float* __restrict__ WT) {
    int i = blockIdx.x * 256 + threadIdx.x;   // 64 blocks * 256 = 16384
    int c = i >> 7, f = i & 127;
    WT[i] = W[(c >> 4) * 2048 + f * 16 + (c & 15)];
}

// ---------------- k1: h = x @ W via SCALAR W loads
// 256-thread blocks (4 waves); all waves cover the same 64 nodes (lane = node,
// x fetched once -> L1 shared); wave w computes cols [32w, 32w+32) = heads 2w,2w+1.
// cbase goes through readfirstlane -> provably SGPR-uniform -> WT rows s_load.
// h is written as packed bf16 (2 cols per uint).
__global__ __launch_bounds__(256, 3) void k1_gemm(const float* __restrict__ x,
                                                  const float* __restrict__ WT,
                                                  const float* __restrict__ a,
                                                  unsigned* __restrict__ h16,
                                                  float* __restrict__ s_src,
                                                  float* __restrict__ s_tgt) {
    int t = threadIdx.x;
    int lane = t & 63;
    int n = blockIdx.x * 64 + lane;           // 782*64 = 50048 >= 50000
    bool valid = (n < N_NODES);
    int nn = valid ? n : (N_NODES - 1);       // clamp: loads always in-bounds
    int cg = __builtin_amdgcn_readfirstlane(t >> 6);   // 0..3, SGPR-uniform

    float4 xq[32];
    {
        const float4* xg = (const float4*)(x + (size_t)nn * 128);
#pragma unroll
        for (int j = 0; j < 32; j++) xq[j] = xg[j];
    }

    int cbase = cg * 32;
    float ps0 = 0.f, pt0 = 0.f, ps1 = 0.f, pt1 = 0.f;
#pragma unroll 1
    for (int cp = 0; cp < 16; cp++) {
        int c0 = cbase + 2 * cp, c1 = c0 + 1;
        const float* wt0 = WT + (size_t)c0 * 128;   // uniform (sgpr cbase + cp)
        const float* wt1 = WT + (size_t)c1 * 128;   // uniform
        float a0e = 0.f, a0o = 0.f, a1e = 0.f, a1o = 0.f;
#pragma unroll
        for (int j = 0; j < 32; j++) {
            float4 xv = xq[j];
            a0e = fmaf(xv.x, wt0[4 * j],     a0e);
            a0o = fmaf(xv.y, wt0[4 * j + 1], a0o);
            a0e = fmaf(xv.z, wt0[4 * j + 2], a0e);
            a0o = fmaf(xv.w, wt0[4 * j + 3], a0o);
            a1e = fmaf(xv.x, wt1[4 * j],     a1e);
            a1o = fmaf(xv.y, wt1[4 * j + 1], a1o);
            a1e = fmaf(xv.z, wt1[4 * j + 2], a1e);
            a1o = fmaf(xv.w, wt1[4 * j + 3], a1o);
        }
        float h0 = a0e + a0o, h1 = a1e + a1o;
        if (valid)
            h16[(size_t)n * 64 + (c0 >> 1)] = f2bf(h0) | (f2bf(h1) << 16);

        int hd = c0 >> 4, d0 = c0 & 15;       // c1 same head, d0+1
        float as0 = a[hd * 32 + d0],     at0 = a[hd * 32 + 16 + d0];
        float as1 = a[hd * 32 + d0 + 1], at1 = a[hd * 32 + 16 + d0 + 1];
        float pss = fmaf(h0, as0, h1 * as1);
        float ptt = fmaf(h0, at0, h1 * at1);
        if (cp < 8) { ps0 += pss; pt0 += ptt; }
        else        { ps1 += pss; pt1 += ptt; }
    }
    if (valid) {
        int hh = 2 * cg;
        s_src[(size_t)n * 8 + hh]     = ps0;  s_tgt[(size_t)n * 8 + hh]     = pt0;
        s_src[(size_t)n * 8 + hh + 1] = ps1;  s_tgt[(size_t)n * 8 + hh + 1] = pt1;
    }
}

// ---------------- maxred stage 1: per-block partial per-head maxes (no atomics)
__global__ __launch_bounds__(256) void k_maxred1(const float* __restrict__ s_src,
                                                 const float* __restrict__ s_tgt,
                                                 float* __restrict__ part_ss,
                                                 float* __restrict__ part_st) {
    __shared__ float red[2][4][8];
    int t = threadIdx.x;
    int i = blockIdx.x * 256 + t;   // 1563*256 >= 400000
    float vs = -INFINITY, vt = -INFINITY;
    if (i < N_NODES * 8) { vs = s_src[i]; vt = s_tgt[i]; }
#pragma unroll
    for (int off = 8; off < 64; off <<= 1) {
        vs = fmaxf(vs, __shfl_xor(vs, off, 64));
        vt = fmaxf(vt, __shfl_xor(vt, off, 64));
    }
    int lane = t & 63, wave = t >> 6;
    if (lane < 8) { red[0][wave][lane] = vs; red[1][wave][lane] = vt; }
    __syncthreads();
    if (t < 8) {
        float m = fmaxf(fmaxf(red[0][0][t], red[0][1][t]),
                        fmaxf(red[0][2][t], red[0][3][t]));
        part_ss[blockIdx.x * 8 + t] = m;
    } else if (t < 16) {
        int j = t - 8;
        float m = fmaxf(fmaxf(red[1][0][j], red[1][1][j]),
                        fmaxf(red[1][2][j], red[1][3][j]));
        part_st[blockIdx.x * 8 + j] = m;
    }
}

// ---------------- maxred stage 2: one block reduces 1563*8 partials
__global__ __launch_bounds__(256) void k_maxred2(const float* __restrict__ part_ss,
                                                 const float* __restrict__ part_st,
                                                 float* __restrict__ maxss,
                                                 float* __restrict__ maxst) {
    __shared__ float red[2][4][8];
    int t = threadIdx.x;
    const int TOT = 1563 * 8;
    float vs = -INFINITY, vt = -INFINITY;
    for (int j = t; j < TOT; j += 256) {   // stride 256 % 8 == 0 keeps head = t&7
        vs = fmaxf(vs, part_ss[j]);
        vt = fmaxf(vt, part_st[j]);
    }
#pragma unroll
    for (int off = 8; off < 64; off <<= 1) {
        vs = fmaxf(vs, __shfl_xor(vs, off, 64));
        vt = fmaxf(vt, __shfl_xor(vt, off, 64));
    }
    int lane = t & 63, wave = t >> 6;
    if (lane < 8) { red[0][wave][lane] = vs; red[1][wave][lane] = vt; }
    __syncthreads();
    if (t < 8) {
        maxss[t] = fmaxf(fmaxf(red[0][0][t], red[0][1][t]),
                         fmaxf(red[0][2][t], red[0][3][t]));
    } else if (t < 16) {
        int j = t - 8;
        maxst[j] = fmaxf(fmaxf(red[1][0][j], red[1][1][j]),
                         fmaxf(red[1][2][j], red[1][3][j]));
    }
}

// ---------------- hist: deg[tgt]++
__global__ __launch_bounds__(256) void k_hist(const int* __restrict__ tgtA,
                                              int* __restrict__ deg) {
    int e = blockIdx.x * 256 + threadIdx.x;
    atomicAdd(&deg[tgtA[e]], 1);
}

// ---------------- scan1: per-block (256-node chunk) sums
__global__ __launch_bounds__(256) void k_scan1(const int* __restrict__ deg,
                                               int* __restrict__ bsum) {
    __shared__ int wsum[4];
    int t = threadIdx.x;
    int idx = blockIdx.x * 256 + t;
    int v = (idx < N_NODES) ? deg[idx] : 0;
#pragma unroll
    for (int off = 1; off < 64; off <<= 1) v += __shfl_xor(v, off, 64);
    int lane = t & 63, w = t >> 6;
    if (lane == 0) wsum[w] = v;
    __syncthreads();
    if (t == 0) bsum[blockIdx.x] = wsum[0] + wsum[1] + wsum[2] + wsum[3];
}

// ---------------- scan2: exclusive scan of 196 block sums
__global__ __launch_bounds__(256) void k_scan2(const int* __restrict__ bsum,
                                               int* __restrict__ boff,
                                               int* __restrict__ rowptr) {
    __shared__ int wsum[4];
    __shared__ int woff[4];
    int t = threadIdx.x, lane = t & 63, w = t >> 6;
    int v = (t < 196) ? bsum[t] : 0;
    int inc = v;
#pragma unroll
    for (int off = 1; off < 64; off <<= 1) {
        int nn = __shfl_up(inc, off, 64);
        if (lane >= off) inc += nn;
    }
    if (lane == 63) wsum[w] = inc;
    __syncthreads();
    if (t == 0) {
        woff[0] = 0;
        woff[1] = wsum[0];
        woff[2] = wsum[0] + wsum[1];
        woff[3] = wsum[0] + wsum[1] + wsum[2];
    }
    __syncthreads();
    if (t < 196) boff[t] = woff[w] + inc - v;
    if (t == 0) rowptr[N_NODES] = N_EDGES;
}

// ---------------- scan3: local exclusive scan + block offset -> rowptr/cursor
__global__ __launch_bounds__(256) void k_scan3(const int* __restrict__ deg,
                                               const int* __restrict__ boff,
                                               int* __restrict__ rowptr,
                                               int* __restrict__ cursor) {
    __shared__ int wsum[4];
    __shared__ int woff[4];
    int t = threadIdx.x, lane = t & 63, w = t >> 6;
    int idx = blockIdx.x * 256 + t;
    int v = (idx < N_NODES) ? deg[idx] : 0;
    int inc = v;
#pragma unroll
    for (int off = 1; off < 64; off <<= 1) {
        int nn = __shfl_up(inc, off, 64);
        if (lane >= off) inc += nn;
    }
    if (lane == 63) wsum[w] = inc;
    __syncthreads();
    if (t == 0) {
        woff[0] = 0;
        woff[1] = wsum[0];
        woff[2] = wsum[0] + wsum[1];
        woff[3] = wsum[0] + wsum[1] + wsum[2];
    }
    __syncthreads();
    int excl = boff[blockIdx.x] + woff[w] + inc - v;
    if (idx < N_NODES) { rowptr[idx] = excl; cursor[idx] = excl; }
}

// ---------------- scatter: src_sorted by tgt (lean, 4-edge ILP)
__global__ __launch_bounds__(256) void k_scatter(const int* __restrict__ srcA,
                                                 const int* __restrict__ tgtA,
                                                 int* __restrict__ cursor,
                                                 int* __restrict__ src_sorted) {
    int base = blockIdx.x * 1024 + threadIdx.x;
    int e0 = base, e1 = base + 256, e2 = base + 512, e3 = base + 768;
    if (e3 < N_EDGES) {
        int s0 = srcA[e0], s1 = srcA[e1], s2 = srcA[e2], s3 = srcA[e3];
        int t0 = tgtA[e0], t1 = tgtA[e1], t2 = tgtA[e2], t3 = tgtA[e3];
        int p0 = atomicAdd(&cursor[t0], 1);
        int p1 = atomicAdd(&cursor[t1], 1);
        int p2 = atomicAdd(&cursor[t2], 1);
        int p3 = atomicAdd(&cursor[t3], 1);
        src_sorted[p0] = s0;
        src_sorted[p1] = s1;
        src_sorted[p2] = s2;
        src_sorted[p3] = s3;
    } else {
#pragma unroll
        for (int k = 0; k < 4; k++) {
            int e = base + k * 256;
            if (e < N_EDGES) {
                int s = srcA[e], tg = tgtA[e];
                int p = atomicAdd(&cursor[tg], 1);
                src_sorted[p] = s;
            }
        }
    }
}

// ---------------- fused: per-node atomic-free softmax + aggregation + bias
// one wave per node; lane owns cols 2*lane, 2*lane+1 (single head = lane>>3)
// h is packed bf16: one uint per lane per edge.
__global__ __launch_bounds__(256) void k_fused(const int* __restrict__ rowptr,
                                               const int* __restrict__ src_sorted,
                                               const float* __restrict__ s_src,
                                               const float* __restrict__ s_tgt,
                                               const float* __restrict__ maxss,
                                               const float* __restrict__ maxst,
                                               const unsigned* __restrict__ h16,
                                               const float* __restrict__ bias,
                                               float* __restrict__ outb) {
    int t = threadIdx.x;
    int wave = t >> 6, lane = t & 63;
    int n = blockIdx.x * 4 + wave;   // 12500*4 == 50000
    int head = lane >> 3;
    int c = 2 * lane;

    float mh = maxss[head] + maxst[head];
    float st = s_tgt[(size_t)n * 8 + head];
    int begin = rowptr[n], end = rowptr[n + 1];

    float accx = 0.f, accy = 0.f, den = 0.f;
    int e = begin;
    for (; e + 1 < end; e += 2) {
        int sA = src_sorted[e];
        int sB = src_sorted[e + 1];
        float ssA = s_src[(size_t)sA * 8 + head];
        float ssB = s_src[(size_t)sB * 8 + head];
        unsigned pA = h16[(size_t)sA * 64 + lane];
        unsigned pB = h16[(size_t)sB * 64 + lane];
        float vA = ssA + st; vA = vA >= 0.f ? vA : ALPHA * vA;
        float vB = ssB + st; vB = vB >= 0.f ? vB : ALPHA * vB;
        float exA = __expf(fminf(fmaxf(vA - mh, -20.f), 20.f));
        float exB = __expf(fminf(fmaxf(vB - mh, -20.f), 20.f));
        den += exA + exB;
        accx = fmaf(exA, bf2f(pA & 0xffffu), fmaf(exB, bf2f(pB & 0xffffu), accx));
        accy = fmaf(exA, bf2f(pA >> 16),     fmaf(exB, bf2f(pB >> 16),     accy));
    }
    if (e < end) {
        int sA = src_sorted[e];
        float ssA = s_src[(size_t)sA * 8 + head];
        unsigned pA = h16[(size_t)sA * 64 + lane];
        float vA = ssA + st; vA = vA >= 0.f ? vA : ALPHA * vA;
        float exA = __expf(fminf(fmaxf(vA - mh, -20.f), 20.f));
        den += exA;
        accx = fmaf(exA, bf2f(pA & 0xffffu), accx);
        accy = fmaf(exA, bf2f(pA >> 16),     accy);
    }
    float r = 1.f / (den + EPSV);
    float2 o;
    o.x = accx * r + bias[c];
    o.y = accy * r + bias[c + 1];
    *(float2*)(outb + (size_t)n * 128 + c) = o;
}

extern "C" void kernel_launch(void* const* d_in, const int* in_sizes, int n_in,
                              void* d_out, int out_size, void* d_ws, size_t ws_size,
                              hipStream_t stream) {
    const float* x    = (const float*)d_in[0];
    const int*   ei   = (const int*)d_in[1];
    const float* W    = (const float*)d_in[2];
    const float* a    = (const float*)d_in[3];
    const float* bias = (const float*)d_in[4];
    float* outb = (float*)d_out;

    char* ws = (char*)d_ws;
    // layout (bytes):
    unsigned* h16     = (unsigned*)(ws);                 // 12,800,000
    float* s_src      = (float*)(ws + 12800000);         //  1,600,000
    float* s_tgt      = (float*)(ws + 14400000);         //  1,600,000
    int*   deg        = (int*)  (ws + 16000000);         //    200,064
    int*   rowptr     = (int*)  (ws + 16200064);         //    200,064
    int*   cursor     = (int*)  (ws + 16400128);         //    200,064
    int*   src_sorted = (int*)  (ws + 16600192);         //  3,200,000
    int*   bsum       = (int*)  (ws + 19800192);         //      1,024
    int*   boff       = (int*)  (ws + 19801216);         //      1,024
    float* part_ss    = (float*)(ws + 19802240);         //     50,176
    float* part_st    = (float*)(ws + 19852416);         //     50,176
    float* maxss      = (float*)(ws + 19902592);         //         32
    float* maxst      = (float*)(ws + 19902624);         //         32
    float* WT         = (float*)(ws + 19902656);         //     65,536

    const int* srcA = ei;
    const int* tgtA = ei + N_EDGES;

    hipLaunchKernelGGL(k_init,    dim3(196),   dim3(256), 0, stream, deg);
    hipLaunchKernelGGL(k_wt,      dim3(64),    dim3(256), 0, stream, W, WT);
    hipLaunchKernelGGL(k1_gemm,   dim3(782),   dim3(256), 0, stream, x, WT, a, h16, s_src, s_tgt);
    hipLaunchKernelGGL(k_hist,    dim3(3125),  dim3(256), 0, stream, tgtA, deg);
    hipLaunchKernelGGL(k_maxred1, dim3(1563),  dim3(256), 0, stream, s_src, s_tgt, part_ss, part_st);
    hipLaunchKernelGGL(k_maxred2, dim3(1),     dim3(256), 0, stream, part_ss, part_st, maxss, maxst);
    hipLaunchKernelGGL(k_scan1,   dim3(196),   dim3(256), 0, stream, deg, bsum);
    hipLaunchKernelGGL(k_scan2,   dim3(1),     dim3(256), 0, stream, bsum, boff, rowptr);
    hipLaunchKernelGGL(k_scan3,   dim3(196),   dim3(256), 0, stream, deg, boff, rowptr, cursor);
    hipLaunchKernelGGL(k_scatter, dim3(782),   dim3(256), 0, stream, srcA, tgtA, cursor, src_sorted);
    hipLaunchKernelGGL(k_fused,   dim3(12500), dim3(256), 0, stream, rowptr, src_sorted, s_src, s_tgt, maxss, maxst, h16, bias, outb);
}

// Round 10
// 279.624 us; speedup vs baseline: 2.3574x; 2.3574x over previous
//
#include <hip/hip_runtime.h>
#include <stdint.h>

#define N_NODES 50000
#define N_EDGES 800000
#define IN_F 128
#define HEADS 8
#define HEAD_DIM 16
#define ALPHA 0.2f
#define EPSV 1e-6f

typedef short short8 __attribute__((ext_vector_type(8)));
typedef float floatx4 __attribute__((ext_vector_type(4)));

__device__ __forceinline__ float bf2f(unsigned v) {
    return __uint_as_float(v << 16);
}
__device__ __forceinline__ unsigned f2bf(float f) {
    unsigned u = __float_as_uint(f);
    return (u + 0x7fffu + ((u >> 16) & 1u)) >> 16;
}

// ---------------- init: zero deg
__global__ __launch_bounds__(256) void k_init(int* __restrict__ deg) {
    int i = blockIdx.x * 256 + threadIdx.x;
    if (i < N_NODES) deg[i] = 0;
}

// ---------------- x2b: x fp32 -> bf16
__global__ __launch_bounds__(256) void k_x2b(const float* __restrict__ x,
                                             ushort* __restrict__ xb) {
    int i = blockIdx.x * 256 + threadIdx.x;   // 6250*256 = 1.6M float4s
    const float4* xf = (const float4*)x;
    float4 v = xf[i];
    ushort4 o;
    o.x = (ushort)f2bf(v.x);
    o.y = (ushort)f2bf(v.y);
    o.z = (ushort)f2bf(v.z);
    o.w = (ushort)f2bf(v.w);
    ((ushort4*)xb)[i] = o;
}

// ---------------- wt: W[h][f][d] fp32 -> WTb[c][f] bf16  (c = h*16+d)
__global__ __launch_bounds__(256) void k_wt(const float* __restrict__ W,
                                            ushort* __restrict__ WTb) {
    int i = blockIdx.x * 256 + threadIdx.x;   // 64 blocks * 256 = 16384
    int c = i >> 7, f = i & 127;
    WTb[i] = (ushort)f2bf(W[(c >> 4) * 2048 + f * 16 + (c & 15)]);
}

// ---------------- k1: h = x @ W via MFMA 16x16x32 bf16
// 4 waves/block; wave w -> nodes [nb, nb+16), all 128 cols (8 col-tiles).
// A-frag: m=lane&15, k=quad*8+j (16B contig from xb row).
// B-frag: n=lane&15, k=quad*8+j; B[k=f][n=c]=WTb[c][f] (16B contig, L1-resident).
// D: col=lane&15, row=quad*4+reg.  h stored as bf16 ushort [n][128].
__global__ __launch_bounds__(256) void k1_mfma(const ushort* __restrict__ xb,
                                               const ushort* __restrict__ WTb,
                                               ushort* __restrict__ hb) {
    int t = threadIdx.x;
    int wave = t >> 6, lane = t & 63;
    int quad = lane >> 4, col = lane & 15;
    int nb = blockIdx.x * 64 + wave * 16;     // 782*64 = 50048 >= 50000

    int na = nb + col;                        // a-frag node (m index)
    int nac = na < N_NODES ? na : (N_NODES - 1);
    const ushort* xrow = xb + (size_t)nac * 128 + quad * 8;

    floatx4 acc[8];
    floatx4 z = {0.f, 0.f, 0.f, 0.f};
#pragma unroll
    for (int ct = 0; ct < 8; ct++) acc[ct] = z;

#pragma unroll
    for (int kc = 0; kc < 4; kc++) {
        short8 af = *(const short8*)(xrow + kc * 32);
#pragma unroll
        for (int ct = 0; ct < 8; ct++) {
            const ushort* wrow = WTb + (size_t)(ct * 16 + col) * 128 + kc * 32 + quad * 8;
            short8 bf = *(const short8*)wrow;
            acc[ct] = __builtin_amdgcn_mfma_f32_16x16x32_bf16(af, bf, acc[ct], 0, 0, 0);
        }
    }

#pragma unroll
    for (int r = 0; r < 4; r++) {
        int node = nb + quad * 4 + r;
        if (node < N_NODES) {
            ushort* hrow = hb + (size_t)node * 128 + col;
#pragma unroll
            for (int ct = 0; ct < 8; ct++)
                hrow[ct * 16] = (ushort)f2bf(acc[ct][r]);
        }
    }
}

// ---------------- k_s: s_src/s_tgt from bf16 h
__global__ __launch_bounds__(256) void k_s(const ushort* __restrict__ hb,
                                           const float* __restrict__ a,
                                           float* __restrict__ s_src,
                                           float* __restrict__ s_tgt) {
    int i = blockIdx.x * 256 + threadIdx.x;   // 1563*256 >= 400000
    if (i >= N_NODES * 8) return;
    int n = i >> 3, hd = i & 7;
    const uint4* hp = (const uint4*)(hb + (size_t)n * 128 + hd * 16);
    uint4 p0 = hp[0], p1 = hp[1];
    unsigned w[8] = {p0.x, p0.y, p0.z, p0.w, p1.x, p1.y, p1.z, p1.w};
    float ss = 0.f, st = 0.f;
#pragma unroll
    for (int j = 0; j < 8; j++) {
        float h0 = bf2f(w[j] & 0xffffu);
        float h1 = bf2f(w[j] >> 16);
        int d = 2 * j;
        ss = fmaf(h0, a[hd * 32 + d],      fmaf(h1, a[hd * 32 + d + 1],      ss));
        st = fmaf(h0, a[hd * 32 + 16 + d], fmaf(h1, a[hd * 32 + 16 + d + 1], st));
    }
    s_src[i] = ss;
    s_tgt[i] = st;
}

// ---------------- maxred stage 1: per-block partial per-head maxes (no atomics)
__global__ __launch_bounds__(256) void k_maxred1(const float* __restrict__ s_src,
                                                 const float* __restrict__ s_tgt,
                                                 float* __restrict__ part_ss,
                                                 float* __restrict__ part_st) {
    __shared__ float red[2][4][8];
    int t = threadIdx.x;
    int i = blockIdx.x * 256 + t;   // 1563*256 >= 400000
    float vs = -INFINITY, vt = -INFINITY;
    if (i < N_NODES * 8) { vs = s_src[i]; vt = s_tgt[i]; }
#pragma unroll
    for (int off = 8; off < 64; off <<= 1) {
        vs = fmaxf(vs, __shfl_xor(vs, off, 64));
        vt = fmaxf(vt, __shfl_xor(vt, off, 64));
    }
    int lane = t & 63, wave = t >> 6;
    if (lane < 8) { red[0][wave][lane] = vs; red[1][wave][lane] = vt; }
    __syncthreads();
    if (t < 8) {
        float m = fmaxf(fmaxf(red[0][0][t], red[0][1][t]),
                        fmaxf(red[0][2][t], red[0][3][t]));
        part_ss[blockIdx.x * 8 + t] = m;
    } else if (t < 16) {
        int j = t - 8;
        float m = fmaxf(fmaxf(red[1][0][j], red[1][1][j]),
                        fmaxf(red[1][2][j], red[1][3][j]));
        part_st[blockIdx.x * 8 + j] = m;
    }
}

// ---------------- maxred stage 2: one block reduces 1563*8 partials
__global__ __launch_bounds__(256) void k_maxred2(const float* __restrict__ part_ss,
                                                 const float* __restrict__ part_st,
                                                 float* __restrict__ maxss,
                                                 float* __restrict__ maxst) {
    __shared__ float red[2][4][8];
    int t = threadIdx.x;
    const int TOT = 1563 * 8;
    float vs = -INFINITY, vt = -INFINITY;
    for (int j = t; j < TOT; j += 256) {   // stride 256 % 8 == 0 keeps head = t&7
        vs = fmaxf(vs, part_ss[j]);
        vt = fmaxf(vt, part_st[j]);
    }
#pragma unroll
    for (int off = 8; off < 64; off <<= 1) {
        vs = fmaxf(vs, __shfl_xor(vs, off, 64));
        vt = fmaxf(vt, __shfl_xor(vt, off, 64));
    }
    int lane = t & 63, wave = t >> 6;
    if (lane < 8) { red[0][wave][lane] = vs; red[1][wave][lane] = vt; }
    __syncthreads();
    if (t < 8) {
        maxss[t] = fmaxf(fmaxf(red[0][0][t], red[0][1][t]),
                         fmaxf(red[0][2][t], red[0][3][t]));
    } else if (t < 16) {
        int j = t - 8;
        maxst[j] = fmaxf(fmaxf(red[1][0][j], red[1][1][j]),
                         fmaxf(red[1][2][j], red[1][3][j]));
    }
}

// ---------------- hist: deg[tgt]++
__global__ __launch_bounds__(256) void k_hist(const int* __restrict__ tgtA,
                                              int* __restrict__ deg) {
    int e = blockIdx.x * 256 + threadIdx.x;
    atomicAdd(&deg[tgtA[e]], 1);
}

// ---------------- scan1: per-block (256-node chunk) sums
__global__ __launch_bounds__(256) void k_scan1(const int* __restrict__ deg,
                                               int* __restrict__ bsum) {
    __shared__ int wsum[4];
    int t = threadIdx.x;
    int idx = blockIdx.x * 256 + t;
    int v = (idx < N_NODES) ? deg[idx] : 0;
#pragma unroll
    for (int off = 1; off < 64; off <<= 1) v += __shfl_xor(v, off, 64);
    int lane = t & 63, w = t >> 6;
    if (lane == 0) wsum[w] = v;
    __syncthreads();
    if (t == 0) bsum[blockIdx.x] = wsum[0] + wsum[1] + wsum[2] + wsum[3];
}

// ---------------- scan2: exclusive scan of 196 block sums
__global__ __launch_bounds__(256) void k_scan2(const int* __restrict__ bsum,
                                               int* __restrict__ boff,
                                               int* __restrict__ rowptr) {
    __shared__ int wsum[4];
    __shared__ int woff[4];
    int t = threadIdx.x, lane = t & 63, w = t >> 6;
    int v = (t < 196) ? bsum[t] : 0;
    int inc = v;
#pragma unroll
    for (int off = 1; off < 64; off <<= 1) {
        int nn = __shfl_up(inc, off, 64);
        if (lane >= off) inc += nn;
    }
    if (lane == 63) wsum[w] = inc;
    __syncthreads();
    if (t == 0) {
        woff[0] = 0;
        woff[1] = wsum[0];
        woff[2] = wsum[0] + wsum[1];
        woff[3] = wsum[0] + wsum[1] + wsum[2];
    }
    __syncthreads();
    if (t < 196) boff[t] = woff[w] + inc - v;
    if (t == 0) rowptr[N_NODES] = N_EDGES;
}

// ---------------- scan3: local exclusive scan + block offset -> rowptr/cursor
__global__ __launch_bounds__(256) void k_scan3(const int* __restrict__ deg,
                                               const int* __restrict__ boff,
                                               int* __restrict__ rowptr,
                                               int* __restrict__ cursor) {
    __shared__ int wsum[4];
    __shared__ int woff[4];
    int t = threadIdx.x, lane = t & 63, w = t >> 6;
    int idx = blockIdx.x * 256 + t;
    int v = (idx < N_NODES) ? deg[idx] : 0;
    int inc = v;
#pragma unroll
    for (int off = 1; off < 64; off <<= 1) {
        int nn = __shfl_up(inc, off, 64);
        if (lane >= off) inc += nn;
    }
    if (lane == 63) wsum[w] = inc;
    __syncthreads();
    if (t == 0) {
        woff[0] = 0;
        woff[1] = wsum[0];
        woff[2] = wsum[0] + wsum[1];
        woff[3] = wsum[0] + wsum[1] + wsum[2];
    }
    __syncthreads();
    int excl = boff[blockIdx.x] + woff[w] + inc - v;
    if (idx < N_NODES) { rowptr[idx] = excl; cursor[idx] = excl; }
}

// ---------------- scatter: src_sorted by tgt (lean, 4-edge ILP)
__global__ __launch_bounds__(256) void k_scatter(const int* __restrict__ srcA,
                                                 const int* __restrict__ tgtA,
                                                 int* __restrict__ cursor,
                                                 int* __restrict__ src_sorted) {
    int base = blockIdx.x * 1024 + threadIdx.x;
    int e0 = base, e1 = base + 256, e2 = base + 512, e3 = base + 768;
    if (e3 < N_EDGES) {
        int s0 = srcA[e0], s1 = srcA[e1], s2 = srcA[e2], s3 = srcA[e3];
        int t0 = tgtA[e0], t1 = tgtA[e1], t2 = tgtA[e2], t3 = tgtA[e3];
        int p0 = atomicAdd(&cursor[t0], 1);
        int p1 = atomicAdd(&cursor[t1], 1);
        int p2 = atomicAdd(&cursor[t2], 1);
        int p3 = atomicAdd(&cursor[t3], 1);
        src_sorted[p0] = s0;
        src_sorted[p1] = s1;
        src_sorted[p2] = s2;
        src_sorted[p3] = s3;
    } else {
#pragma unroll
        for (int k = 0; k < 4; k++) {
            int e = base + k * 256;
            if (e < N_EDGES) {
                int s = srcA[e], tg = tgtA[e];
                int p = atomicAdd(&cursor[tg], 1);
                src_sorted[p] = s;
            }
        }
    }
}

// ---------------- fused: per-node atomic-free softmax + aggregation + bias
// one wave per node; lane owns cols 2*lane, 2*lane+1 (single head = lane>>3)
// h is bf16: one uint (2 cols) per lane per edge.
__global__ __launch_bounds__(256) void k_fused(const int* __restrict__ rowptr,
                                               const int* __restrict__ src_sorted,
                                               const float* __restrict__ s_src,
                                               const float* __restrict__ s_tgt,
                                               const float* __restrict__ maxss,
                                               const float* __restrict__ maxst,
                                               const unsigned* __restrict__ h16,
                                               const float* __restrict__ bias,
                                               float* __restrict__ outb) {
    int t = threadIdx.x;
    int wave = t >> 6, lane = t & 63;
    int n = blockIdx.x * 4 + wave;   // 12500*4 == 50000
    int head = lane >> 3;
    int c = 2 * lane;

    float mh = maxss[head] + maxst[head];
    float st = s_tgt[(size_t)n * 8 + head];
    int begin = rowptr[n], end = rowptr[n + 1];

    float accx = 0.f, accy = 0.f, den = 0.f;
    int e = begin;
    for (; e + 1 < end; e += 2) {
        int sA = src_sorted[e];
        int sB = src_sorted[e + 1];
        float ssA = s_src[(size_t)sA * 8 + head];
        float ssB = s_src[(size_t)sB * 8 + head];
        unsigned pA = h16[(size_t)sA * 64 + lane];
        unsigned pB = h16[(size_t)sB * 64 + lane];
        float vA = ssA + st; vA = vA >= 0.f ? vA : ALPHA * vA;
        float vB = ssB + st; vB = vB >= 0.f ? vB : ALPHA * vB;
        float exA = __expf(fminf(fmaxf(vA - mh, -20.f), 20.f));
        float exB = __expf(fminf(fmaxf(vB - mh, -20.f), 20.f));
        den += exA + exB;
        accx = fmaf(exA, bf2f(pA & 0xffffu), fmaf(exB, bf2f(pB & 0xffffu), accx));
        accy = fmaf(exA, bf2f(pA >> 16),     fmaf(exB, bf2f(pB >> 16),     accy));
    }
    if (e < end) {
        int sA = src_sorted[e];
        float ssA = s_src[(size_t)sA * 8 + head];
        unsigned pA = h16[(size_t)sA * 64 + lane];
        float vA = ssA + st; vA = vA >= 0.f ? vA : ALPHA * vA;
        float exA = __expf(fminf(fmaxf(vA - mh, -20.f), 20.f));
        den += exA;
        accx = fmaf(exA, bf2f(pA & 0xffffu), accx);
        accy = fmaf(exA, bf2f(pA >> 16),     accy);
    }
    float r = 1.f / (den + EPSV);
    float2 o;
    o.x = accx * r + bias[c];
    o.y = accy * r + bias[c + 1];
    *(float2*)(outb + (size_t)n * 128 + c) = o;
}

extern "C" void kernel_launch(void* const* d_in, const int* in_sizes, int n_in,
                              void* d_out, int out_size, void* d_ws, size_t ws_size,
                              hipStream_t stream) {
    const float* x    = (const float*)d_in[0];
    const int*   ei   = (const int*)d_in[1];
    const float* W    = (const float*)d_in[2];
    const float* a    = (const float*)d_in[3];
    const float* bias = (const float*)d_in[4];
    float* outb = (float*)d_out;

    char* ws = (char*)d_ws;
    // layout (bytes):
    ushort* hb        = (ushort*)(ws);                   // 12,800,000
    float* s_src      = (float*)(ws + 12800000);         //  1,600,000
    float* s_tgt      = (float*)(ws + 14400000);         //  1,600,000
    int*   deg        = (int*)  (ws + 16000000);         //    200,064
    int*   rowptr     = (int*)  (ws + 16200064);         //    200,064
    int*   cursor     = (int*)  (ws + 16400128);         //    200,064
    int*   src_sorted = (int*)  (ws + 16600192);         //  3,200,000
    int*   bsum       = (int*)  (ws + 19800192);         //      1,024
    int*   boff       = (int*)  (ws + 19801216);         //      1,024
    float* part_ss    = (float*)(ws + 19802240);         //     50,176
    float* part_st    = (float*)(ws + 19852416);         //     50,176
    float* maxss      = (float*)(ws + 19902592);         //         32
    float* maxst      = (float*)(ws + 19902624);         //         32
    ushort* WTb       = (ushort*)(ws + 19902656);        //     32,768
    ushort* xb        = (ushort*)(ws + 19935424);        // 12,800,000

    const int* srcA = ei;
    const int* tgtA = ei + N_EDGES;

    hipLaunchKernelGGL(k_init,    dim3(196),   dim3(256), 0, stream, deg);
    hipLaunchKernelGGL(k_x2b,     dim3(6250),  dim3(256), 0, stream, x, xb);
    hipLaunchKernelGGL(k_wt,      dim3(64),    dim3(256), 0, stream, W, WTb);
    hipLaunchKernelGGL(k1_mfma,   dim3(782),   dim3(256), 0, stream, xb, WTb, hb);
    hipLaunchKernelGGL(k_hist,    dim3(3125),  dim3(256), 0, stream, tgtA, deg);
    hipLaunchKernelGGL(k_s,       dim3(1563),  dim3(256), 0, stream, hb, a, s_src, s_tgt);
    hipLaunchKernelGGL(k_maxred1, dim3(1563),  dim3(256), 0, stream, s_src, s_tgt, part_ss, part_st);
    hipLaunchKernelGGL(k_maxred2, dim3(1),     dim3(256), 0, stream, part_ss, part_st, maxss, maxst);
    hipLaunchKernelGGL(k_scan1,   dim3(196),   dim3(256), 0, stream, deg, bsum);
    hipLaunchKernelGGL(k_scan2,   dim3(1),     dim3(256), 0, stream, bsum, boff, rowptr);
    hipLaunchKernelGGL(k_scan3,   dim3(196),   dim3(256), 0, stream, deg, boff, rowptr, cursor);
    hipLaunchKernelGGL(k_scatter, dim3(782),   dim3(256), 0, stream, srcA, tgtA, cursor, src_sorted);
    hipLaunchKernelGGL(k_fused,   dim3(12500), dim3(256), 0, stream, rowptr, src_sorted, s_src, s_tgt, maxss, maxst, (const unsigned*)hb, bias, outb);
}

// Round 11
// 255.321 us; speedup vs baseline: 2.5818x; 1.0952x over previous
//
#include <hip/hip_runtime.h>
#include <stdint.h>

#define N_NODES 50000
#define N_EDGES 800000
#define IN_F 128
#define HEADS 8
#define HEAD_DIM 16
#define ALPHA 0.2f
#define EPSV 1e-6f

typedef short short8 __attribute__((ext_vector_type(8)));
typedef float floatx4 __attribute__((ext_vector_type(4)));

__device__ __forceinline__ float bf2f(unsigned v) {
    return __uint_as_float(v << 16);
}
__device__ __forceinline__ unsigned f2bf(float f) {
    unsigned u = __float_as_uint(f);
    return (u + 0x7fffu + ((u >> 16) & 1u)) >> 16;
}

// ---------------- wt+init: W[h][f][d] fp32 -> WTb[c][f] bf16 ; zero deg
__global__ __launch_bounds__(256) void k_wt(const float* __restrict__ W,
                                            ushort* __restrict__ WTb,
                                            int* __restrict__ deg) {
    int i = blockIdx.x * 256 + threadIdx.x;   // 196*256 = 50176
    if (i < 16384) {
        int c = i >> 7, f = i & 127;
        WTb[i] = (ushort)f2bf(W[(c >> 4) * 2048 + f * 16 + (c & 15)]);
    }
    if (i < N_NODES) deg[i] = 0;
}

// ---------------- k1: h = x @ W via MFMA 16x16x32 bf16, x converted inline,
// s_src/s_tgt computed in epilogue via 16-lane reductions.
// 4 waves/block; wave w -> nodes [nb, nb+16), all 128 cols (8 col-tiles).
// A-frag: m=lane&15 (node nb+m), k=quad*8+j. B-frag: n=lane&15, k=quad*8+j.
// D: row(node off)=quad*4+reg, col=ct*16+(lane&15).
__global__ __launch_bounds__(256) void k1_mfma(const float* __restrict__ x,
                                               const ushort* __restrict__ WTb,
                                               const float* __restrict__ a,
                                               ushort* __restrict__ hb,
                                               float* __restrict__ s_src,
                                               float* __restrict__ s_tgt) {
    int t = threadIdx.x;
    int wave = t >> 6, lane = t & 63;
    int quad = lane >> 4, col = lane & 15;
    int nb = blockIdx.x * 64 + wave * 16;     // 782*64 = 50048 >= 50000

    int na = nb + col;                        // a-frag node (m index)
    int nac = na < N_NODES ? na : (N_NODES - 1);
    const float* xrow = x + (size_t)nac * 128 + quad * 8;

    floatx4 acc[8];
    floatx4 z = {0.f, 0.f, 0.f, 0.f};
#pragma unroll
    for (int ct = 0; ct < 8; ct++) acc[ct] = z;

#pragma unroll
    for (int kc = 0; kc < 4; kc++) {
        float4 f0 = *(const float4*)(xrow + kc * 32);
        float4 f1 = *(const float4*)(xrow + kc * 32 + 4);
        short8 af;
        af[0] = (short)f2bf(f0.x); af[1] = (short)f2bf(f0.y);
        af[2] = (short)f2bf(f0.z); af[3] = (short)f2bf(f0.w);
        af[4] = (short)f2bf(f1.x); af[5] = (short)f2bf(f1.y);
        af[6] = (short)f2bf(f1.z); af[7] = (short)f2bf(f1.w);
#pragma unroll
        for (int ct = 0; ct < 8; ct++) {
            const ushort* wrow = WTb + (size_t)(ct * 16 + col) * 128 + kc * 32 + quad * 8;
            short8 bf = *(const short8*)wrow;
            acc[ct] = __builtin_amdgcn_mfma_f32_16x16x32_bf16(af, bf, acc[ct], 0, 0, 0);
        }
    }

    // a-vector fragments: a_s[ct] for this lane's col, a_t likewise
    float af_s[8], af_t[8];
#pragma unroll
    for (int ct = 0; ct < 8; ct++) {
        af_s[ct] = a[ct * 32 + col];
        af_t[ct] = a[ct * 32 + 16 + col];
    }

#pragma unroll
    for (int r = 0; r < 4; r++) {
        int node = nb + quad * 4 + r;
        bool nv = (node < N_NODES);
        if (nv) {
            ushort* hrow = hb + (size_t)node * 128 + col;
#pragma unroll
            for (int ct = 0; ct < 8; ct++)
                hrow[ct * 16] = (ushort)f2bf(acc[ct][r]);
        }
        // s projections: reduce over the 16 lanes of this quad
        float ps[8], pt[8];
#pragma unroll
        for (int ct = 0; ct < 8; ct++) {
            float hs = acc[ct][r];
            float vs = hs * af_s[ct];
            float vt = hs * af_t[ct];
#pragma unroll
            for (int off = 1; off < 16; off <<= 1) {
                vs += __shfl_xor(vs, off, 64);
                vt += __shfl_xor(vt, off, 64);
            }
            ps[ct] = vs; pt[ct] = vt;
        }
        if (nv && col == 0) {
            float4 s0 = make_float4(ps[0], ps[1], ps[2], ps[3]);
            float4 s1 = make_float4(ps[4], ps[5], ps[6], ps[7]);
            float4 t0 = make_float4(pt[0], pt[1], pt[2], pt[3]);
            float4 t1 = make_float4(pt[4], pt[5], pt[6], pt[7]);
            *(float4*)(s_src + (size_t)node * 8)     = s0;
            *(float4*)(s_src + (size_t)node * 8 + 4) = s1;
            *(float4*)(s_tgt + (size_t)node * 8)     = t0;
            *(float4*)(s_tgt + (size_t)node * 8 + 4) = t1;
        }
    }
}

// ---------------- maxred stage 1: per-block partial per-head maxes (no atomics)
__global__ __launch_bounds__(256) void k_maxred1(const float* __restrict__ s_src,
                                                 const float* __restrict__ s_tgt,
                                                 float* __restrict__ part_ss,
                                                 float* __restrict__ part_st) {
    __shared__ float red[2][4][8];
    int t = threadIdx.x;
    int i = blockIdx.x * 256 + t;   // 1563*256 >= 400000
    float vs = -INFINITY, vt = -INFINITY;
    if (i < N_NODES * 8) { vs = s_src[i]; vt = s_tgt[i]; }
#pragma unroll
    for (int off = 8; off < 64; off <<= 1) {
        vs = fmaxf(vs, __shfl_xor(vs, off, 64));
        vt = fmaxf(vt, __shfl_xor(vt, off, 64));
    }
    int lane = t & 63, wave = t >> 6;
    if (lane < 8) { red[0][wave][lane] = vs; red[1][wave][lane] = vt; }
    __syncthreads();
    if (t < 8) {
        float m = fmaxf(fmaxf(red[0][0][t], red[0][1][t]),
                        fmaxf(red[0][2][t], red[0][3][t]));
        part_ss[blockIdx.x * 8 + t] = m;
    } else if (t < 16) {
        int j = t - 8;
        float m = fmaxf(fmaxf(red[1][0][j], red[1][1][j]),
                        fmaxf(red[1][2][j], red[1][3][j]));
        part_st[blockIdx.x * 8 + j] = m;
    }
}

// ---------------- maxred stage 2: one block reduces 1563*8 partials
__global__ __launch_bounds__(256) void k_maxred2(const float* __restrict__ part_ss,
                                                 const float* __restrict__ part_st,
                                                 float* __restrict__ maxss,
                                                 float* __restrict__ maxst) {
    __shared__ float red[2][4][8];
    int t = threadIdx.x;
    const int TOT = 1563 * 8;
    float vs = -INFINITY, vt = -INFINITY;
    for (int j = t; j < TOT; j += 256) {   // stride 256 % 8 == 0 keeps head = t&7
        vs = fmaxf(vs, part_ss[j]);
        vt = fmaxf(vt, part_st[j]);
    }
#pragma unroll
    for (int off = 8; off < 64; off <<= 1) {
        vs = fmaxf(vs, __shfl_xor(vs, off, 64));
        vt = fmaxf(vt, __shfl_xor(vt, off, 64));
    }
    int lane = t & 63, wave = t >> 6;
    if (lane < 8) { red[0][wave][lane] = vs; red[1][wave][lane] = vt; }
    __syncthreads();
    if (t < 8) {
        maxss[t] = fmaxf(fmaxf(red[0][0][t], red[0][1][t]),
                         fmaxf(red[0][2][t], red[0][3][t]));
    } else if (t < 16) {
        int j = t - 8;
        maxst[j] = fmaxf(fmaxf(red[1][0][j], red[1][1][j]),
                         fmaxf(red[1][2][j], red[1][3][j]));
    }
}

// ---------------- hist: deg[tgt]++
__global__ __launch_bounds__(256) void k_hist(const int* __restrict__ tgtA,
                                              int* __restrict__ deg) {
    int e = blockIdx.x * 256 + threadIdx.x;
    atomicAdd(&deg[tgtA[e]], 1);
}

// ---------------- scan1: per-block (256-node chunk) sums
__global__ __launch_bounds__(256) void k_scan1(const int* __restrict__ deg,
                                               int* __restrict__ bsum) {
    __shared__ int wsum[4];
    int t = threadIdx.x;
    int idx = blockIdx.x * 256 + t;
    int v = (idx < N_NODES) ? deg[idx] : 0;
#pragma unroll
    for (int off = 1; off < 64; off <<= 1) v += __shfl_xor(v, off, 64);
    int lane = t & 63, w = t >> 6;
    if (lane == 0) wsum[w] = v;
    __syncthreads();
    if (t == 0) bsum[blockIdx.x] = wsum[0] + wsum[1] + wsum[2] + wsum[3];
}

// ---------------- scan2: exclusive scan of 196 block sums
__global__ __launch_bounds__(256) void k_scan2(const int* __restrict__ bsum,
                                               int* __restrict__ boff,
                                               int* __restrict__ rowptr) {
    __shared__ int wsum[4];
    __shared__ int woff[4];
    int t = threadIdx.x, lane = t & 63, w = t >> 6;
    int v = (t < 196) ? bsum[t] : 0;
    int inc = v;
#pragma unroll
    for (int off = 1; off < 64; off <<= 1) {
        int nn = __shfl_up(inc, off, 64);
        if (lane >= off) inc += nn;
    }
    if (lane == 63) wsum[w] = inc;
    __syncthreads();
    if (t == 0) {
        woff[0] = 0;
        woff[1] = wsum[0];
        woff[2] = wsum[0] + wsum[1];
        woff[3] = wsum[0] + wsum[1] + wsum[2];
    }
    __syncthreads();
    if (t < 196) boff[t] = woff[w] + inc - v;
    if (t == 0) rowptr[N_NODES] = N_EDGES;
}

// ---------------- scan3: local exclusive scan + block offset -> rowptr/cursor
__global__ __launch_bounds__(256) void k_scan3(const int* __restrict__ deg,
                                               const int* __restrict__ boff,
                                               int* __restrict__ rowptr,
                                               int* __restrict__ cursor) {
    __shared__ int wsum[4];
    __shared__ int woff[4];
    int t = threadIdx.x, lane = t & 63, w = t >> 6;
    int idx = blockIdx.x * 256 + t;
    int v = (idx < N_NODES) ? deg[idx] : 0;
    int inc = v;
#pragma unroll
    for (int off = 1; off < 64; off <<= 1) {
        int nn = __shfl_up(inc, off, 64);
        if (lane >= off) inc += nn;
    }
    if (lane == 63) wsum[w] = inc;
    __syncthreads();
    if (t == 0) {
        woff[0] = 0;
        woff[1] = wsum[0];
        woff[2] = wsum[0] + wsum[1];
        woff[3] = wsum[0] + wsum[1] + wsum[2];
    }
    __syncthreads();
    int excl = boff[blockIdx.x] + woff[w] + inc - v;
    if (idx < N_NODES) { rowptr[idx] = excl; cursor[idx] = excl; }
}

// ---------------- scatter: src_sorted by tgt (lean, 4-edge ILP)
__global__ __launch_bounds__(256) void k_scatter(const int* __restrict__ srcA,
                                                 const int* __restrict__ tgtA,
                                                 int* __restrict__ cursor,
                                                 int* __restrict__ src_sorted) {
    int base = blockIdx.x * 1024 + threadIdx.x;
    int e0 = base, e1 = base + 256, e2 = base + 512, e3 = base + 768;
    if (e3 < N_EDGES) {
        int s0 = srcA[e0], s1 = srcA[e1], s2 = srcA[e2], s3 = srcA[e3];
        int t0 = tgtA[e0], t1 = tgtA[e1], t2 = tgtA[e2], t3 = tgtA[e3];
        int p0 = atomicAdd(&cursor[t0], 1);
        int p1 = atomicAdd(&cursor[t1], 1);
        int p2 = atomicAdd(&cursor[t2], 1);
        int p3 = atomicAdd(&cursor[t3], 1);
        src_sorted[p0] = s0;
        src_sorted[p1] = s1;
        src_sorted[p2] = s2;
        src_sorted[p3] = s3;
    } else {
#pragma unroll
        for (int k = 0; k < 4; k++) {
            int e = base + k * 256;
            if (e < N_EDGES) {
                int s = srcA[e], tg = tgtA[e];
                int p = atomicAdd(&cursor[tg], 1);
                src_sorted[p] = s;
            }
        }
    }
}

// ---------------- fused: per-node atomic-free softmax + aggregation + bias
// TWO nodes per wave (32 lanes each). Half-lane hl owns cols 4*hl..4*hl+3
// (one uint2 = 4 bf16 cols), head = hl>>2.
__global__ __launch_bounds__(256) void k_fused(const int* __restrict__ rowptr,
                                               const int* __restrict__ src_sorted,
                                               const float* __restrict__ s_src,
                                               const float* __restrict__ s_tgt,
                                               const float* __restrict__ maxss,
                                               const float* __restrict__ maxst,
                                               const unsigned* __restrict__ h16,
                                               const float* __restrict__ bias,
                                               float* __restrict__ outb) {
    int t = threadIdx.x;
    int wave = t >> 6, lane = t & 63;
    int half = lane >> 5, hl = lane & 31;
    int n = blockIdx.x * 8 + wave * 2 + half;   // 6250*8 == 50000
    int head = hl >> 2;
    int c = 4 * hl;

    const uint2* h2 = (const uint2*)h16;

    float mh = maxss[head] + maxst[head];
    float st = s_tgt[(size_t)n * 8 + head];
    int begin = rowptr[n], end = rowptr[n + 1];

    float ax = 0.f, ay = 0.f, az = 0.f, aw = 0.f, den = 0.f;
    int e = begin;
    for (; e + 1 < end; e += 2) {
        int sA = src_sorted[e];
        int sB = src_sorted[e + 1];
        float ssA = s_src[(size_t)sA * 8 + head];
        float ssB = s_src[(size_t)sB * 8 + head];
        uint2 pA = h2[(size_t)sA * 32 + hl];
        uint2 pB = h2[(size_t)sB * 32 + hl];
        float vA = ssA + st; vA = vA >= 0.f ? vA : ALPHA * vA;
        float vB = ssB + st; vB = vB >= 0.f ? vB : ALPHA * vB;
        float exA = __expf(fminf(fmaxf(vA - mh, -20.f), 20.f));
        float exB = __expf(fminf(fmaxf(vB - mh, -20.f), 20.f));
        den += exA + exB;
        ax = fmaf(exA, bf2f(pA.x & 0xffffu), fmaf(exB, bf2f(pB.x & 0xffffu), ax));
        ay = fmaf(exA, bf2f(pA.x >> 16),     fmaf(exB, bf2f(pB.x >> 16),     ay));
        az = fmaf(exA, bf2f(pA.y & 0xffffu), fmaf(exB, bf2f(pB.y & 0xffffu), az));
        aw = fmaf(exA, bf2f(pA.y >> 16),     fmaf(exB, bf2f(pB.y >> 16),     aw));
    }
    if (e < end) {
        int sA = src_sorted[e];
        float ssA = s_src[(size_t)sA * 8 + head];
        uint2 pA = h2[(size_t)sA * 32 + hl];
        float vA = ssA + st; vA = vA >= 0.f ? vA : ALPHA * vA;
        float exA = __expf(fminf(fmaxf(vA - mh, -20.f), 20.f));
        den += exA;
        ax = fmaf(exA, bf2f(pA.x & 0xffffu), ax);
        ay = fmaf(exA, bf2f(pA.x >> 16),     ay);
        az = fmaf(exA, bf2f(pA.y & 0xffffu), az);
        aw = fmaf(exA, bf2f(pA.y >> 16),     aw);
    }
    float r = 1.f / (den + EPSV);
    float4 b = *(const float4*)(bias + c);
    float4 o;
    o.x = ax * r + b.x;
    o.y = ay * r + b.y;
    o.z = az * r + b.z;
    o.w = aw * r + b.w;
    *(float4*)(outb + (size_t)n * 128 + c) = o;
}

extern "C" void kernel_launch(void* const* d_in, const int* in_sizes, int n_in,
                              void* d_out, int out_size, void* d_ws, size_t ws_size,
                              hipStream_t stream) {
    const float* x    = (const float*)d_in[0];
    const int*   ei   = (const int*)d_in[1];
    const float* W    = (const float*)d_in[2];
    const float* a    = (const float*)d_in[3];
    const float* bias = (const float*)d_in[4];
    float* outb = (float*)d_out;

    char* ws = (char*)d_ws;
    // layout (bytes):
    ushort* hb        = (ushort*)(ws);                   // 12,800,000
    float* s_src      = (float*)(ws + 12800000);         //  1,600,000
    float* s_tgt      = (float*)(ws + 14400000);         //  1,600,000
    int*   deg        = (int*)  (ws + 16000000);         //    200,064
    int*   rowptr     = (int*)  (ws + 16200064);         //    200,064
    int*   cursor     = (int*)  (ws + 16400128);         //    200,064
    int*   src_sorted = (int*)  (ws + 16600192);         //  3,200,000
    int*   bsum       = (int*)  (ws + 19800192);         //      1,024
    int*   boff       = (int*)  (ws + 19801216);         //      1,024
    float* part_ss    = (float*)(ws + 19802240);         //     50,176
    float* part_st    = (float*)(ws + 19852416);         //     50,176
    float* maxss      = (float*)(ws + 19902592);         //         32
    float* maxst      = (float*)(ws + 19902624);         //         32
    ushort* WTb       = (ushort*)(ws + 19902656);        //     32,768

    const int* srcA = ei;
    const int* tgtA = ei + N_EDGES;

    hipLaunchKernelGGL(k_wt,      dim3(196),   dim3(256), 0, stream, W, WTb, deg);
    hipLaunchKernelGGL(k1_mfma,   dim3(782),   dim3(256), 0, stream, x, WTb, a, hb, s_src, s_tgt);
    hipLaunchKernelGGL(k_hist,    dim3(3125),  dim3(256), 0, stream, tgtA, deg);
    hipLaunchKernelGGL(k_maxred1, dim3(1563),  dim3(256), 0, stream, s_src, s_tgt, part_ss, part_st);
    hipLaunchKernelGGL(k_maxred2, dim3(1),     dim3(256), 0, stream, part_ss, part_st, maxss, maxst);
    hipLaunchKernelGGL(k_scan1,   dim3(196),   dim3(256), 0, stream, deg, bsum);
    hipLaunchKernelGGL(k_scan2,   dim3(1),     dim3(256), 0, stream, bsum, boff, rowptr);
    hipLaunchKernelGGL(k_scan3,   dim3(196),   dim3(256), 0, stream, deg, boff, rowptr, cursor);
    hipLaunchKernelGGL(k_scatter, dim3(782),   dim3(256), 0, stream, srcA, tgtA, cursor, src_sorted);
    hipLaunchKernelGGL(k_fused,   dim3(6250),  dim3(256), 0, stream, rowptr, src_sorted, s_src, s_tgt, maxss, maxst, (const unsigned*)hb, bias, outb);
}

// Round 12
// 194.448 us; speedup vs baseline: 3.3901x; 1.3131x over previous
//
#include <hip/hip_runtime.h>
#include <stdint.h>

#define N_NODES 50000
#define N_EDGES 800000
#define IN_F 128
#define HEADS 8
#define HEAD_DIM 16
#define ALPHA 0.2f
#define EPSV 1e-6f

#define NB 196          // buckets = tgt >> 8
#define CAP 4800        // per-bucket capacity (mean 4096, sigma ~64 -> 11 sigma)

typedef short short8 __attribute__((ext_vector_type(8)));
typedef float floatx4 __attribute__((ext_vector_type(4)));

__device__ __forceinline__ float bf2f(unsigned v) {
    return __uint_as_float(v << 16);
}
__device__ __forceinline__ unsigned f2bf(float f) {
    unsigned u = __float_as_uint(f);
    return (u + 0x7fffu + ((u >> 16) & 1u)) >> 16;
}

// ---------------- wt: W[h][f][d] fp32 -> WTb[c][f] bf16 ; zero gcnt
__global__ __launch_bounds__(256) void k_wt(const float* __restrict__ W,
                                            ushort* __restrict__ WTb,
                                            int* __restrict__ gcnt) {
    int i = blockIdx.x * 256 + threadIdx.x;   // 64*256 = 16384
    int c = i >> 7, f = i & 127;
    WTb[i] = (ushort)f2bf(W[(c >> 4) * 2048 + f * 16 + (c & 15)]);
    if (i < NB) gcnt[i] = 0;
}

// ---------------- k1: h = x @ W via MFMA 16x16x32 bf16 (x converted inline,
// s_src/s_tgt in epilogue). Same as R11 (verified).
__global__ __launch_bounds__(256) void k1_mfma(const float* __restrict__ x,
                                               const ushort* __restrict__ WTb,
                                               const float* __restrict__ a,
                                               ushort* __restrict__ hb,
                                               float* __restrict__ s_src,
                                               float* __restrict__ s_tgt) {
    int t = threadIdx.x;
    int wave = t >> 6, lane = t & 63;
    int quad = lane >> 4, col = lane & 15;
    int nb = blockIdx.x * 64 + wave * 16;     // 782*64 = 50048 >= 50000

    int na = nb + col;
    int nac = na < N_NODES ? na : (N_NODES - 1);
    const float* xrow = x + (size_t)nac * 128 + quad * 8;

    floatx4 acc[8];
    floatx4 z = {0.f, 0.f, 0.f, 0.f};
#pragma unroll
    for (int ct = 0; ct < 8; ct++) acc[ct] = z;

#pragma unroll
    for (int kc = 0; kc < 4; kc++) {
        float4 f0 = *(const float4*)(xrow + kc * 32);
        float4 f1 = *(const float4*)(xrow + kc * 32 + 4);
        short8 af;
        af[0] = (short)f2bf(f0.x); af[1] = (short)f2bf(f0.y);
        af[2] = (short)f2bf(f0.z); af[3] = (short)f2bf(f0.w);
        af[4] = (short)f2bf(f1.x); af[5] = (short)f2bf(f1.y);
        af[6] = (short)f2bf(f1.z); af[7] = (short)f2bf(f1.w);
#pragma unroll
        for (int ct = 0; ct < 8; ct++) {
            const ushort* wrow = WTb + (size_t)(ct * 16 + col) * 128 + kc * 32 + quad * 8;
            short8 bf = *(const short8*)wrow;
            acc[ct] = __builtin_amdgcn_mfma_f32_16x16x32_bf16(af, bf, acc[ct], 0, 0, 0);
        }
    }

    float af_s[8], af_t[8];
#pragma unroll
    for (int ct = 0; ct < 8; ct++) {
        af_s[ct] = a[ct * 32 + col];
        af_t[ct] = a[ct * 32 + 16 + col];
    }

#pragma unroll
    for (int r = 0; r < 4; r++) {
        int node = nb + quad * 4 + r;
        bool nv = (node < N_NODES);
        if (nv) {
            ushort* hrow = hb + (size_t)node * 128 + col;
#pragma unroll
            for (int ct = 0; ct < 8; ct++)
                hrow[ct * 16] = (ushort)f2bf(acc[ct][r]);
        }
        float ps[8], pt[8];
#pragma unroll
        for (int ct = 0; ct < 8; ct++) {
            float hs = acc[ct][r];
            float vs = hs * af_s[ct];
            float vt = hs * af_t[ct];
#pragma unroll
            for (int off = 1; off < 16; off <<= 1) {
                vs += __shfl_xor(vs, off, 64);
                vt += __shfl_xor(vt, off, 64);
            }
            ps[ct] = vs; pt[ct] = vt;
        }
        if (nv && col == 0) {
            *(float4*)(s_src + (size_t)node * 8)     = make_float4(ps[0], ps[1], ps[2], ps[3]);
            *(float4*)(s_src + (size_t)node * 8 + 4) = make_float4(ps[4], ps[5], ps[6], ps[7]);
            *(float4*)(s_tgt + (size_t)node * 8)     = make_float4(pt[0], pt[1], pt[2], pt[3]);
            *(float4*)(s_tgt + (size_t)node * 8 + 4) = make_float4(pt[4], pt[5], pt[6], pt[7]);
        }
    }
}

// ---------------- passA: bucket edges by tgt>>8, packed (tgt&255)<<16 | src
__global__ __launch_bounds__(256) void k_passA(const int* __restrict__ srcA,
                                               const int* __restrict__ tgtA,
                                               int* __restrict__ gcnt,
                                               unsigned* __restrict__ bucketbuf) {
    __shared__ int lcnt[NB];
    __shared__ int lbase[NB];
    int t = threadIdx.x;
    if (t < NB) lcnt[t] = 0;
    __syncthreads();

    int base = blockIdx.x * 2048 + t;   // 391 blocks * 2048 = 800768
    int tg[8], sr[8];
    bool vld[8];
#pragma unroll
    for (int k = 0; k < 8; k++) {
        int e = base + k * 256;
        vld[k] = (e < N_EDGES);
        int ee = vld[k] ? e : 0;
        tg[k] = tgtA[ee];
        sr[k] = srcA[ee];
    }
#pragma unroll
    for (int k = 0; k < 8; k++)
        if (vld[k]) atomicAdd(&lcnt[tg[k] >> 8], 1);
    __syncthreads();
    if (t < NB) {
        int c = lcnt[t];
        lbase[t] = (c > 0) ? atomicAdd(&gcnt[t], c) : 0;
        lcnt[t] = 0;
    }
    __syncthreads();
#pragma unroll
    for (int k = 0; k < 8; k++) {
        if (vld[k]) {
            int b = tg[k] >> 8;
            int off = atomicAdd(&lcnt[b], 1);
            int pos = lbase[b] + off;
            if (pos < CAP)
                bucketbuf[(size_t)b * CAP + pos] =
                    ((unsigned)(tg[k] & 255) << 16) | (unsigned)sr[k];
        }
    }
}

// ---------------- scan2: exclusive scan of NB bucket counts -> bbase
__global__ __launch_bounds__(256) void k_scan2(const int* __restrict__ gcnt,
                                               int* __restrict__ bbase,
                                               int* __restrict__ rowptr) {
    __shared__ int wsum[4];
    __shared__ int woff[4];
    int t = threadIdx.x, lane = t & 63, w = t >> 6;
    int v = (t < NB) ? gcnt[t] : 0;
    int inc = v;
#pragma unroll
    for (int off = 1; off < 64; off <<= 1) {
        int nn = __shfl_up(inc, off, 64);
        if (lane >= off) inc += nn;
    }
    if (lane == 63) wsum[w] = inc;
    __syncthreads();
    if (t == 0) {
        woff[0] = 0;
        woff[1] = wsum[0];
        woff[2] = wsum[0] + wsum[1];
        woff[3] = wsum[0] + wsum[1] + wsum[2];
    }
    __syncthreads();
    if (t < NB) bbase[t] = woff[w] + inc - v;
    if (t == 0) rowptr[N_NODES] = N_EDGES;
}

// ---------------- passB: per-bucket LDS counting sort -> rowptr + src16
__global__ __launch_bounds__(256) void k_passB(const unsigned* __restrict__ bucketbuf,
                                               const int* __restrict__ gcnt,
                                               const int* __restrict__ bbase,
                                               int* __restrict__ rowptr,
                                               ushort* __restrict__ src16) {
    __shared__ int bin[256];
    __shared__ int ebin[256];
    __shared__ int wsum[4];
    __shared__ int woff[4];
    __shared__ ushort stage[CAP];
    int t = threadIdx.x, lane = t & 63, w = t >> 6;
    int b = blockIdx.x;
    int n = gcnt[b]; if (n > CAP) n = CAP;
    int base = bbase[b];
    const unsigned* buf = bucketbuf + (size_t)b * CAP;

    bin[t] = 0;
    __syncthreads();
    for (int i = t; i < n; i += 256)
        atomicAdd(&bin[buf[i] >> 16], 1);
    __syncthreads();
    // exclusive scan over 256 bins
    int v = bin[t];
    int inc = v;
#pragma unroll
    for (int off = 1; off < 64; off <<= 1) {
        int nn = __shfl_up(inc, off, 64);
        if (lane >= off) inc += nn;
    }
    if (lane == 63) wsum[w] = inc;
    __syncthreads();
    if (t == 0) {
        woff[0] = 0;
        woff[1] = wsum[0];
        woff[2] = wsum[0] + wsum[1];
        woff[3] = wsum[0] + wsum[1] + wsum[2];
    }
    __syncthreads();
    int excl = woff[w] + inc - v;
    ebin[t] = excl;
    int node = b * 256 + t;
    if (node < N_NODES) rowptr[node] = base + excl;
    __syncthreads();
    bin[t] = ebin[t];   // cursor
    __syncthreads();
    for (int i = t; i < n; i += 256) {
        unsigned p = buf[i];
        int off = atomicAdd(&bin[p >> 16], 1);
        stage[off] = (ushort)(p & 0xffffu);
    }
    __syncthreads();
    for (int i = t; i < n; i += 256)
        src16[base + i] = stage[i];
}

// ---------------- maxred stage 1: per-block partial per-head maxes
__global__ __launch_bounds__(256) void k_maxred1(const float* __restrict__ s_src,
                                                 const float* __restrict__ s_tgt,
                                                 float* __restrict__ part_ss,
                                                 float* __restrict__ part_st) {
    __shared__ float red[2][4][8];
    int t = threadIdx.x;
    int i = blockIdx.x * 256 + t;   // 1563*256 >= 400000
    float vs = -INFINITY, vt = -INFINITY;
    if (i < N_NODES * 8) { vs = s_src[i]; vt = s_tgt[i]; }
#pragma unroll
    for (int off = 8; off < 64; off <<= 1) {
        vs = fmaxf(vs, __shfl_xor(vs, off, 64));
        vt = fmaxf(vt, __shfl_xor(vt, off, 64));
    }
    int lane = t & 63, wave = t >> 6;
    if (lane < 8) { red[0][wave][lane] = vs; red[1][wave][lane] = vt; }
    __syncthreads();
    if (t < 8) {
        float m = fmaxf(fmaxf(red[0][0][t], red[0][1][t]),
                        fmaxf(red[0][2][t], red[0][3][t]));
        part_ss[blockIdx.x * 8 + t] = m;
    } else if (t < 16) {
        int j = t - 8;
        float m = fmaxf(fmaxf(red[1][0][j], red[1][1][j]),
                        fmaxf(red[1][2][j], red[1][3][j]));
        part_st[blockIdx.x * 8 + j] = m;
    }
}

// ---------------- maxred stage 2
__global__ __launch_bounds__(256) void k_maxred2(const float* __restrict__ part_ss,
                                                 const float* __restrict__ part_st,
                                                 float* __restrict__ maxss,
                                                 float* __restrict__ maxst) {
    __shared__ float red[2][4][8];
    int t = threadIdx.x;
    const int TOT = 1563 * 8;
    float vs = -INFINITY, vt = -INFINITY;
    for (int j = t; j < TOT; j += 256) {
        vs = fmaxf(vs, part_ss[j]);
        vt = fmaxf(vt, part_st[j]);
    }
#pragma unroll
    for (int off = 8; off < 64; off <<= 1) {
        vs = fmaxf(vs, __shfl_xor(vs, off, 64));
        vt = fmaxf(vt, __shfl_xor(vt, off, 64));
    }
    int lane = t & 63, wave = t >> 6;
    if (lane < 8) { red[0][wave][lane] = vs; red[1][wave][lane] = vt; }
    __syncthreads();
    if (t < 8) {
        maxss[t] = fmaxf(fmaxf(red[0][0][t], red[0][1][t]),
                         fmaxf(red[0][2][t], red[0][3][t]));
    } else if (t < 16) {
        int j = t - 8;
        maxst[j] = fmaxf(fmaxf(red[1][0][j], red[1][1][j]),
                         fmaxf(red[1][2][j], red[1][3][j]));
    }
}

// ---------------- fused: TWO nodes per wave (32 lanes each); src16 index
__global__ __launch_bounds__(256) void k_fused(const int* __restrict__ rowptr,
                                               const ushort* __restrict__ src16,
                                               const float* __restrict__ s_src,
                                               const float* __restrict__ s_tgt,
                                               const float* __restrict__ maxss,
                                               const float* __restrict__ maxst,
                                               const unsigned* __restrict__ h16,
                                               const float* __restrict__ bias,
                                               float* __restrict__ outb) {
    int t = threadIdx.x;
    int wave = t >> 6, lane = t & 63;
    int half = lane >> 5, hl = lane & 31;
    int n = blockIdx.x * 8 + wave * 2 + half;   // 6250*8 == 50000
    int head = hl >> 2;
    int c = 4 * hl;

    const uint2* h2 = (const uint2*)h16;

    float mh = maxss[head] + maxst[head];
    float st = s_tgt[(size_t)n * 8 + head];
    int begin = rowptr[n], end = rowptr[n + 1];

    float ax = 0.f, ay = 0.f, az = 0.f, aw = 0.f, den = 0.f;
    int e = begin;
    for (; e + 1 < end; e += 2) {
        int sA = src16[e];
        int sB = src16[e + 1];
        float ssA = s_src[(size_t)sA * 8 + head];
        float ssB = s_src[(size_t)sB * 8 + head];
        uint2 pA = h2[(size_t)sA * 32 + hl];
        uint2 pB = h2[(size_t)sB * 32 + hl];
        float vA = ssA + st; vA = vA >= 0.f ? vA : ALPHA * vA;
        float vB = ssB + st; vB = vB >= 0.f ? vB : ALPHA * vB;
        float exA = __expf(fminf(fmaxf(vA - mh, -20.f), 20.f));
        float exB = __expf(fminf(fmaxf(vB - mh, -20.f), 20.f));
        den += exA + exB;
        ax = fmaf(exA, bf2f(pA.x & 0xffffu), fmaf(exB, bf2f(pB.x & 0xffffu), ax));
        ay = fmaf(exA, bf2f(pA.x >> 16),     fmaf(exB, bf2f(pB.x >> 16),     ay));
        az = fmaf(exA, bf2f(pA.y & 0xffffu), fmaf(exB, bf2f(pB.y & 0xffffu), az));
        aw = fmaf(exA, bf2f(pA.y >> 16),     fmaf(exB, bf2f(pB.y >> 16),     aw));
    }
    if (e < end) {
        int sA = src16[e];
        float ssA = s_src[(size_t)sA * 8 + head];
        uint2 pA = h2[(size_t)sA * 32 + hl];
        float vA = ssA + st; vA = vA >= 0.f ? vA : ALPHA * vA;
        float exA = __expf(fminf(fmaxf(vA - mh, -20.f), 20.f));
        den += exA;
        ax = fmaf(exA, bf2f(pA.x & 0xffffu), ax);
        ay = fmaf(exA, bf2f(pA.x >> 16),     ay);
        az = fmaf(exA, bf2f(pA.y & 0xffffu), az);
        aw = fmaf(exA, bf2f(pA.y >> 16),     aw);
    }
    float r = 1.f / (den + EPSV);
    float4 b = *(const float4*)(bias + c);
    float4 o;
    o.x = ax * r + b.x;
    o.y = ay * r + b.y;
    o.z = az * r + b.z;
    o.w = aw * r + b.w;
    *(float4*)(outb + (size_t)n * 128 + c) = o;
}

extern "C" void kernel_launch(void* const* d_in, const int* in_sizes, int n_in,
                              void* d_out, int out_size, void* d_ws, size_t ws_size,
                              hipStream_t stream) {
    const float* x    = (const float*)d_in[0];
    const int*   ei   = (const int*)d_in[1];
    const float* W    = (const float*)d_in[2];
    const float* a    = (const float*)d_in[3];
    const float* bias = (const float*)d_in[4];
    float* outb = (float*)d_out;

    char* ws = (char*)d_ws;
    // layout (bytes):
    ushort* hb        = (ushort*)(ws);                   // 12,800,000
    float* s_src      = (float*)(ws + 12800000);         //  1,600,000
    float* s_tgt      = (float*)(ws + 14400000);         //  1,600,000
    int*   rowptr     = (int*)  (ws + 16000000);         //    200,064
    ushort* src16     = (ushort*)(ws + 16200064);        //  1,600,000
    int*   gcnt       = (int*)  (ws + 17800064);         //      1,024
    int*   bbase      = (int*)  (ws + 17801088);         //      1,024
    float* part_ss    = (float*)(ws + 17802112);         //     50,176
    float* part_st    = (float*)(ws + 17852288);         //     50,176
    float* maxss      = (float*)(ws + 17902464);         //         32
    float* maxst      = (float*)(ws + 17902496);         //         32
    ushort* WTb       = (ushort*)(ws + 17902528);        //     32,768
    unsigned* bucketbuf = (unsigned*)(ws + 17935296);    //  3,763,200

    const int* srcA = ei;
    const int* tgtA = ei + N_EDGES;

    hipLaunchKernelGGL(k_wt,      dim3(64),    dim3(256), 0, stream, W, WTb, gcnt);
    hipLaunchKernelGGL(k1_mfma,   dim3(782),   dim3(256), 0, stream, x, WTb, a, hb, s_src, s_tgt);
    hipLaunchKernelGGL(k_passA,   dim3(391),   dim3(256), 0, stream, srcA, tgtA, gcnt, bucketbuf);
    hipLaunchKernelGGL(k_maxred1, dim3(1563),  dim3(256), 0, stream, s_src, s_tgt, part_ss, part_st);
    hipLaunchKernelGGL(k_maxred2, dim3(1),     dim3(256), 0, stream, part_ss, part_st, maxss, maxst);
    hipLaunchKernelGGL(k_scan2,   dim3(1),     dim3(256), 0, stream, gcnt, bbase, rowptr);
    hipLaunchKernelGGL(k_passB,   dim3(196),   dim3(256), 0, stream, bucketbuf, gcnt, bbase, rowptr, src16);
    hipLaunchKernelGGL(k_fused,   dim3(6250),  dim3(256), 0, stream, rowptr, src16, s_src, s_tgt, maxss, maxst, (const unsigned*)hb, bias, outb);
}